// Round 1
// baseline (364.798 us; speedup 1.0000x reference)
//
#include <hip/hip_runtime.h>

#define NN 50000
#define NE 800000
#define NB 16384

// ---------------- DNN GEMM: hdnn = x1 @ dnn_W  (bias dropped: cancels in BN) ----
// 256 blocks x 256 thr. Block b owns rows [b*64, b*64+64). Wave wv handles
// k-chunk [wv*64,(wv+1)*64); lane = row. W loads are wave-uniform -> s_load.
__global__ __launch_bounds__(256) void dnn_gemm(const float* __restrict__ X,
    const float* __restrict__ W, float* __restrict__ H)
{
    __shared__ float part[4][64 * 65];          // stride 65: conflict-free
    const int tid = threadIdx.x;
    const int lane = tid & 63;
    const int wv = __builtin_amdgcn_readfirstlane(tid >> 6);
    const int row = blockIdx.x * 64 + lane;
    float acc[64];
#pragma unroll
    for (int j = 0; j < 64; ++j) acc[j] = 0.f;
    const float4* xr = reinterpret_cast<const float4*>(X + (size_t)row * 256 + wv * 64);
    const float* Wb = W + wv * 64 * 64;
#pragma unroll 1
    for (int k4 = 0; k4 < 16; ++k4) {
        float4 xv = xr[k4];
        const float* wr = Wb + k4 * 4 * 64;
#pragma unroll
        for (int j = 0; j < 64; ++j) {
            float a = acc[j];
            a = fmaf(xv.x, wr[j],       a);
            a = fmaf(xv.y, wr[64 + j],  a);
            a = fmaf(xv.z, wr[128 + j], a);
            a = fmaf(xv.w, wr[192 + j], a);
            acc[j] = a;
        }
    }
#pragma unroll
    for (int j = 0; j < 64; ++j) part[wv][lane * 65 + j] = acc[j];
    __syncthreads();
    // reduce the 4 k-chunks; coalesced global write
    for (int idx = tid; idx < 4096; idx += 256) {
        int r = idx >> 6, j = idx & 63;
        float v = part[0][r * 65 + j] + part[1][r * 65 + j] +
                  part[2][r * 65 + j] + part[3][r * 65 + j];
        H[(size_t)(blockIdx.x * 64 + r) * 64 + j] = v;
    }
}

// ---------------- BN stats: column sum / sumsq over the batch -------------------
__global__ __launch_bounds__(256) void bn_stats(const float* __restrict__ H,
    float* __restrict__ bnsum, float* __restrict__ bnsumsq)
{
    const int tid = threadIdx.x;
    const int col = tid & 63, rg = tid >> 6;
    float s = 0.f, q = 0.f;
    for (int row = blockIdx.x * 4 + rg; row < NB; row += gridDim.x * 4) {
        float v = H[(size_t)row * 64 + col];
        s += v; q += v * v;
    }
    __shared__ float rs[4][64], rq[4][64];
    rs[rg][col] = s; rq[rg][col] = q;
    __syncthreads();
    if (rg == 0) {
        atomicAdd(&bnsum[col],  rs[0][col] + rs[1][col] + rs[2][col] + rs[3][col]);
        atomicAdd(&bnsumsq[col], rq[0][col] + rq[1][col] + rq[2][col] + rq[3][col]);
    }
}

// ---------------- GCN1 GEMM: h1 = x2 @ gcn1_W ----------------------------------
// wave = 64 rows x 64 cols, full K=64. 196 blocks x 4 waves cover 50176 rows.
__global__ __launch_bounds__(256) void gcn1_gemm(const float* __restrict__ X,
    const float* __restrict__ W, float* __restrict__ H)
{
    const int tid = threadIdx.x;
    const int lane = tid & 63;
    const int wv = __builtin_amdgcn_readfirstlane(tid >> 6);
    const int row = (blockIdx.x * 4 + wv) * 64 + lane;
    if (row >= NN) return;                       // no __syncthreads below
    float acc[64];
#pragma unroll
    for (int j = 0; j < 64; ++j) acc[j] = 0.f;
    const float4* xr = reinterpret_cast<const float4*>(X + (size_t)row * 64);
#pragma unroll 1
    for (int k4 = 0; k4 < 16; ++k4) {
        float4 xv = xr[k4];
        const float* wr = W + k4 * 4 * 64;
#pragma unroll
        for (int j = 0; j < 64; ++j) {
            float a = acc[j];
            a = fmaf(xv.x, wr[j],       a);
            a = fmaf(xv.y, wr[64 + j],  a);
            a = fmaf(xv.z, wr[128 + j], a);
            a = fmaf(xv.w, wr[192 + j], a);
            acc[j] = a;
        }
    }
    float4* hr = reinterpret_cast<float4*>(H + (size_t)row * 64);
#pragma unroll
    for (int j4 = 0; j4 < 16; ++j4)
        hr[j4] = make_float4(acc[4*j4], acc[4*j4+1], acc[4*j4+2], acc[4*j4+3]);
}

// ---------------- degree (in-degree by col, +1 self-loop added later) ----------
__global__ void deg_kernel(const int* __restrict__ ei, float* __restrict__ deg)
{
    for (int e = blockIdx.x * blockDim.x + threadIdx.x; e < NE;
         e += gridDim.x * blockDim.x)
        atomicAdd(&deg[ei[NE + e]], 1.0f);
}

__global__ void dis_kernel(float* deg)
{
    int i = blockIdx.x * blockDim.x + threadIdx.x;
    if (i < NN) deg[i] = rsqrtf(deg[i] + 1.0f);  // in-place deg -> deg^{-1/2}
}

// ---------------- edge pass: agg[col] += norm * h1[row]; wraw[row] += dis[col] --
__global__ __launch_bounds__(256) void edge_pass(const int* __restrict__ ei,
    const float* __restrict__ dis, const float* __restrict__ h1,
    float* __restrict__ agg, float* __restrict__ wraw)
{
    const int lane = threadIdx.x & 63;
    const int grp = threadIdx.x >> 6;
    for (int e = blockIdx.x * 4 + grp; e < NE; e += gridDim.x * 4) {
        int r = ei[e], c = ei[NE + e];
        float dc = dis[c];
        float nrm = dis[r] * dc;
        float v = nrm * h1[(size_t)r * 64 + lane];
        atomicAdd(&agg[(size_t)c * 64 + lane], v);
        if (lane == 0) atomicAdd(&wraw[r], dc);
    }
}

// ---------------- node pass: svec = sum_i coef_i * relu(gcn1_out_i) ------------
__global__ __launch_bounds__(256) void node_pass(const float* __restrict__ h1,
    const float* __restrict__ agg, const float* __restrict__ dis,
    const float* __restrict__ wraw, const float* __restrict__ b1,
    float* __restrict__ svec)
{
    const int lane = threadIdx.x & 63;
    const int grp = threadIdx.x >> 6;
    float accv = 0.f;
    const float bl = b1[lane];
    for (int i = blockIdx.x * 4 + grp; i < NN; i += gridDim.x * 4) {
        float d = dis[i];
        float coef = d * wraw[i] + d * d;
        float g = agg[(size_t)i * 64 + lane] + d * d * h1[(size_t)i * 64 + lane] + bl;
        accv += coef * fmaxf(g, 0.f);
    }
    __shared__ float red[4][64];
    red[grp][lane] = accv;
    __syncthreads();
    if (grp == 0)
        atomicAdd(&svec[lane], red[0][lane] + red[1][lane] + red[2][lane] + red[3][lane]);
}

// ---------------- finalize: BN scale/shift, gnn_emb, v_dnn, scalar const -------
__global__ void finalize_kernel(const float* __restrict__ bnsum,
    const float* __restrict__ bnsumsq, const float* __restrict__ gamma,
    const float* __restrict__ beta, const float* __restrict__ svec,
    const float* __restrict__ g2W, const float* __restrict__ g2b,
    const float* __restrict__ fc1W, const float* __restrict__ fc1b,
    const float* __restrict__ fc2W, const float* __restrict__ fc2b,
    float* __restrict__ scale, float* __restrict__ shift,
    float* __restrict__ vdnn, float* __restrict__ cons)
{
    int j = threadIdx.x;                         // 64 threads, 1 wave
    float mu = bnsum[j] * (1.0f / NB);
    float var = bnsumsq[j] * (1.0f / NB) - mu * mu;
    float sc = rsqrtf(var + 1e-5f) * gamma[j];
    scale[j] = sc;
    shift[j] = beta[j] - mu * sc;
    // gnn_emb[j] = (svec @ gcn2_W)[j]/N + gcn2_b[j]
    float ge = 0.f;
    for (int k = 0; k < 64; ++k) ge += svec[k] * g2W[k * 64 + j];
    ge = ge * (1.0f / NN) + g2b[j];
    // v = fc1_W @ fc2_W  (split dnn/gnn halves)
    float vd = 0.f, vg = 0.f;
    for (int k = 0; k < 64; ++k) {
        vd += fc1W[j * 64 + k] * fc2W[k];
        vg += fc1W[(64 + j) * 64 + k] * fc2W[k];
    }
    vdnn[j] = vd;
    float part = ge * vg + fc1b[j] * fc2W[j];
    for (int o = 32; o > 0; o >>= 1) part += __shfl_down(part, o);
    if (j == 0) cons[0] = part + fc2b[0];
}

// ---------------- output: out[i] = sum_j relu(h*sc+sh)*vdnn + C ----------------
__global__ __launch_bounds__(256) void out_kernel(const float* __restrict__ H,
    const float* __restrict__ scale, const float* __restrict__ shift,
    const float* __restrict__ vdnn, const float* __restrict__ cons,
    float* __restrict__ out)
{
    const int lane = threadIdx.x & 63;
    const int grp = threadIdx.x >> 6;
    const int i = blockIdx.x * 4 + grp;
    float x = H[(size_t)i * 64 + lane] * scale[lane] + shift[lane];
    x = fmaxf(x, 0.f) * vdnn[lane];
    for (int o = 32; o > 0; o >>= 1) x += __shfl_down(x, o);
    if (lane == 0) out[i] = x + cons[0];
}

extern "C" void kernel_launch(void* const* d_in, const int* in_sizes, int n_in,
                              void* d_out, int out_size, void* d_ws, size_t ws_size,
                              hipStream_t stream)
{
    const float* x1    = (const float*)d_in[0];
    const float* x2    = (const float*)d_in[1];
    const int*   ei    = (const int*)d_in[2];
    const float* dnnW  = (const float*)d_in[3];
    // d_in[4] = dnn_b: cancels inside BatchNorm, unused
    const float* gamma = (const float*)d_in[5];
    const float* beta  = (const float*)d_in[6];
    const float* g1W   = (const float*)d_in[7];
    const float* g1b   = (const float*)d_in[8];
    const float* g2W   = (const float*)d_in[9];
    const float* g2b   = (const float*)d_in[10];
    const float* fc1W  = (const float*)d_in[11];
    const float* fc1b  = (const float*)d_in[12];
    const float* fc2W  = (const float*)d_in[13];
    const float* fc2b  = (const float*)d_in[14];

    float* ws      = (float*)d_ws;
    float* h1      = ws;                   // 3,200,000
    float* hdnn    = h1 + 3200000;         // 1,048,576
    float* agg     = hdnn + 1048576;       // 3,200,000  <- zero region start
    float* deg     = agg + 3200000;        // 50,048
    float* wraw    = deg + 50048;          // 50,048
    float* bnsum   = wraw + 50048;         // 64
    float* bnsumsq = bnsum + 64;           // 64
    float* svec    = bnsumsq + 64;         // 64         <- zero region end
    float* scale   = svec + 64;
    float* shift   = scale + 64;
    float* vdnn    = shift + 64;
    float* cons    = vdnn + 64;

    const size_t zero_bytes = (size_t)(3200000 + 50048 + 50048 + 192) * sizeof(float);
    hipMemsetAsync(agg, 0, zero_bytes, stream);

    dnn_gemm<<<256, 256, 0, stream>>>(x1, dnnW, hdnn);
    bn_stats<<<256, 256, 0, stream>>>(hdnn, bnsum, bnsumsq);
    gcn1_gemm<<<196, 256, 0, stream>>>(x2, g1W, h1);
    deg_kernel<<<1024, 256, 0, stream>>>(ei, deg);
    dis_kernel<<<196, 256, 0, stream>>>(deg);
    edge_pass<<<2048, 256, 0, stream>>>(ei, deg, h1, agg, wraw);
    node_pass<<<512, 256, 0, stream>>>(h1, agg, deg, wraw, g1b, svec);
    finalize_kernel<<<1, 64, 0, stream>>>(bnsum, bnsumsq, gamma, beta, svec,
                                          g2W, g2b, fc1W, fc1b, fc2W, fc2b,
                                          scale, shift, vdnn, cons);
    out_kernel<<<4096, 256, 0, stream>>>(hdnn, scale, shift, vdnn, cons,
                                         (float*)d_out);
}

// Round 2
// 276.468 us; speedup vs baseline: 1.3195x; 1.3195x over previous
//
#include <hip/hip_runtime.h>

#define NN 50000
#define NE 800000
#define NB 16384

// ---------------- DNN GEMM: hdnn = x1 @ dnn_W  (bias dropped: cancels in BN) ----
__global__ __launch_bounds__(256) void dnn_gemm(const float* __restrict__ X,
    const float* __restrict__ W, float* __restrict__ H)
{
    __shared__ float part[4][64 * 65];          // stride 65: conflict-free
    const int tid = threadIdx.x;
    const int lane = tid & 63;
    const int wv = __builtin_amdgcn_readfirstlane(tid >> 6);
    const int row = blockIdx.x * 64 + lane;
    float acc[64];
#pragma unroll
    for (int j = 0; j < 64; ++j) acc[j] = 0.f;
    const float4* xr = reinterpret_cast<const float4*>(X + (size_t)row * 256 + wv * 64);
    const float* Wb = W + wv * 64 * 64;
#pragma unroll 1
    for (int k4 = 0; k4 < 16; ++k4) {
        float4 xv = xr[k4];
        const float* wr = Wb + k4 * 4 * 64;
#pragma unroll
        for (int j = 0; j < 64; ++j) {
            float a = acc[j];
            a = fmaf(xv.x, wr[j],       a);
            a = fmaf(xv.y, wr[64 + j],  a);
            a = fmaf(xv.z, wr[128 + j], a);
            a = fmaf(xv.w, wr[192 + j], a);
            acc[j] = a;
        }
    }
#pragma unroll
    for (int j = 0; j < 64; ++j) part[wv][lane * 65 + j] = acc[j];
    __syncthreads();
    for (int idx = tid; idx < 4096; idx += 256) {
        int r = idx >> 6, j = idx & 63;
        float v = part[0][r * 65 + j] + part[1][r * 65 + j] +
                  part[2][r * 65 + j] + part[3][r * 65 + j];
        H[(size_t)(blockIdx.x * 64 + r) * 64 + j] = v;
    }
}

// ---------------- BN stats ------------------------------------------------------
__global__ __launch_bounds__(256) void bn_stats(const float* __restrict__ H,
    float* __restrict__ bnsum, float* __restrict__ bnsumsq)
{
    const int tid = threadIdx.x;
    const int col = tid & 63, rg = tid >> 6;
    float s = 0.f, q = 0.f;
    for (int row = blockIdx.x * 4 + rg; row < NB; row += gridDim.x * 4) {
        float v = H[(size_t)row * 64 + col];
        s += v; q += v * v;
    }
    __shared__ float rs[4][64], rq[4][64];
    rs[rg][col] = s; rq[rg][col] = q;
    __syncthreads();
    if (rg == 0) {
        atomicAdd(&bnsum[col],  rs[0][col] + rs[1][col] + rs[2][col] + rs[3][col]);
        atomicAdd(&bnsumsq[col], rq[0][col] + rq[1][col] + rq[2][col] + rq[3][col]);
    }
}

// ---------------- GCN1 GEMM: h1 = x2 @ gcn1_W ----------------------------------
__global__ __launch_bounds__(256) void gcn1_gemm(const float* __restrict__ X,
    const float* __restrict__ W, float* __restrict__ H)
{
    const int tid = threadIdx.x;
    const int lane = tid & 63;
    const int wv = __builtin_amdgcn_readfirstlane(tid >> 6);
    const int row = (blockIdx.x * 4 + wv) * 64 + lane;
    if (row >= NN) return;
    float acc[64];
#pragma unroll
    for (int j = 0; j < 64; ++j) acc[j] = 0.f;
    const float4* xr = reinterpret_cast<const float4*>(X + (size_t)row * 64);
#pragma unroll 1
    for (int k4 = 0; k4 < 16; ++k4) {
        float4 xv = xr[k4];
        const float* wr = W + k4 * 4 * 64;
#pragma unroll
        for (int j = 0; j < 64; ++j) {
            float a = acc[j];
            a = fmaf(xv.x, wr[j],       a);
            a = fmaf(xv.y, wr[64 + j],  a);
            a = fmaf(xv.z, wr[128 + j], a);
            a = fmaf(xv.w, wr[192 + j], a);
            acc[j] = a;
        }
    }
    float4* hr = reinterpret_cast<float4*>(H + (size_t)row * 64);
#pragma unroll
    for (int j4 = 0; j4 < 16; ++j4)
        hr[j4] = make_float4(acc[4*j4], acc[4*j4+1], acc[4*j4+2], acc[4*j4+3]);
}

// ---------------- CSR build: count, scan, scatter ------------------------------
__global__ void cnt_kernel(const int* __restrict__ ei, int* __restrict__ cnt)
{
    for (int e = blockIdx.x * blockDim.x + threadIdx.x; e < NE;
         e += gridDim.x * blockDim.x)
        atomicAdd(&cnt[ei[NE + e]], 1);
}

__global__ void dis_kernel(const int* __restrict__ cnt, float* __restrict__ dis)
{
    int i = blockIdx.x * blockDim.x + threadIdx.x;
    if (i < NN) dis[i] = rsqrtf((float)cnt[i] + 1.0f);
}

__global__ __launch_bounds__(256) void scan1(const int* __restrict__ cnt,
                                             int* __restrict__ bsum)
{
    int i = blockIdx.x * 256 + threadIdx.x;
    int v = (i < NN) ? cnt[i] : 0;
#pragma unroll
    for (int o = 32; o > 0; o >>= 1) v += __shfl_down(v, o);
    __shared__ int wsum[4];
    if ((threadIdx.x & 63) == 0) wsum[threadIdx.x >> 6] = v;
    __syncthreads();
    if (threadIdx.x == 0) bsum[blockIdx.x] = wsum[0] + wsum[1] + wsum[2] + wsum[3];
}

__global__ __launch_bounds__(256) void scan2(const int* __restrict__ bsum,
                                             int* __restrict__ boff)
{
    __shared__ int s[256];
    int t = threadIdx.x;
    int v = (t < 196) ? bsum[t] : 0;
    s[t] = v; __syncthreads();
    for (int o = 1; o < 256; o <<= 1) {
        int u = (t >= o) ? s[t - o] : 0;
        __syncthreads();
        s[t] += u;
        __syncthreads();
    }
    if (t < 196) boff[t] = s[t] - v;            // exclusive
}

__global__ __launch_bounds__(256) void scan3(const int* __restrict__ cnt,
    const int* __restrict__ boff, int* __restrict__ offs, int* __restrict__ cursor)
{
    __shared__ int s[256];
    int i = blockIdx.x * 256 + threadIdx.x;
    int t = threadIdx.x;
    int v = (i < NN) ? cnt[i] : 0;
    s[t] = v; __syncthreads();
    for (int o = 1; o < 256; o <<= 1) {
        int u = (t >= o) ? s[t - o] : 0;
        __syncthreads();
        s[t] += u;
        __syncthreads();
    }
    int ex = s[t] - v + boff[blockIdx.x];
    if (i < NN) { offs[i] = ex; cursor[i] = ex; }
}

// scatter edges into CSR buckets; fuse wraw[row] += dis[col]
__global__ void scatter_kernel(const int* __restrict__ ei,
    const float* __restrict__ dis, int* __restrict__ cursor,
    int* __restrict__ erow, float* __restrict__ wraw)
{
    for (int e = blockIdx.x * blockDim.x + threadIdx.x; e < NE;
         e += gridDim.x * blockDim.x) {
        int r = ei[e], c = ei[NE + e];
        int pos = atomicAdd(&cursor[c], 1);
        erow[pos] = r;
        atomicAdd(&wraw[r], dis[c]);
    }
}

// ---------------- fused gather + node pass: svec = sum_c coef_c * relu(g_c) ----
__global__ __launch_bounds__(256) void gather_node(const int* __restrict__ offs,
    const int* __restrict__ cnt, const int* __restrict__ erow,
    const float* __restrict__ dis, const float* __restrict__ wraw,
    const float* __restrict__ h1, const float* __restrict__ b1,
    float* __restrict__ svec)
{
    const int lane = threadIdx.x & 63;
    const int wv = __builtin_amdgcn_readfirstlane(threadIdx.x >> 6);
    const int wid = blockIdx.x * 4 + wv;
    const int nw = gridDim.x * 4;
    const float bl = b1[lane];
    float sacc = 0.f;
    for (int c = wid; c < NN; c += nw) {
        const int st = offs[c], n = cnt[c];
        float acc = 0.f;
        int e = st;
        for (; e + 4 <= st + n; e += 4) {
            int r0 = erow[e], r1 = erow[e + 1], r2 = erow[e + 2], r3 = erow[e + 3];
            float d0 = dis[r0], d1 = dis[r1], d2 = dis[r2], d3 = dis[r3];
            float v0 = h1[(size_t)r0 * 64 + lane];
            float v1 = h1[(size_t)r1 * 64 + lane];
            float v2 = h1[(size_t)r2 * 64 + lane];
            float v3 = h1[(size_t)r3 * 64 + lane];
            acc = fmaf(d0, v0, acc);
            acc = fmaf(d1, v1, acc);
            acc = fmaf(d2, v2, acc);
            acc = fmaf(d3, v3, acc);
        }
        for (; e < st + n; ++e) {
            int r = erow[e];
            acc = fmaf(dis[r], h1[(size_t)r * 64 + lane], acc);
        }
        float d = dis[c];
        float g = fmaf(d, acc, fmaf(d * d, h1[(size_t)c * 64 + lane], bl));
        float coef = fmaf(d, wraw[c], d * d);
        sacc += coef * fmaxf(g, 0.f);
    }
    __shared__ float red[4][64];
    red[wv][lane] = sacc;
    __syncthreads();
    if (wv == 0)
        atomicAdd(&svec[lane], red[0][lane] + red[1][lane] + red[2][lane] + red[3][lane]);
}

// ---------------- finalize: BN scale/shift, gnn_emb, v_dnn, scalar const -------
__global__ void finalize_kernel(const float* __restrict__ bnsum,
    const float* __restrict__ bnsumsq, const float* __restrict__ gamma,
    const float* __restrict__ beta, const float* __restrict__ svec,
    const float* __restrict__ g2W, const float* __restrict__ g2b,
    const float* __restrict__ fc1W, const float* __restrict__ fc1b,
    const float* __restrict__ fc2W, const float* __restrict__ fc2b,
    float* __restrict__ scale, float* __restrict__ shift,
    float* __restrict__ vdnn, float* __restrict__ cons)
{
    int j = threadIdx.x;                         // 64 threads, 1 wave
    float mu = bnsum[j] * (1.0f / NB);
    float var = bnsumsq[j] * (1.0f / NB) - mu * mu;
    float sc = rsqrtf(var + 1e-5f) * gamma[j];
    scale[j] = sc;
    shift[j] = beta[j] - mu * sc;
    float ge = 0.f;
    for (int k = 0; k < 64; ++k) ge += svec[k] * g2W[k * 64 + j];
    ge = ge * (1.0f / NN) + g2b[j];
    float vd = 0.f, vg = 0.f;
    for (int k = 0; k < 64; ++k) {
        vd += fc1W[j * 64 + k] * fc2W[k];
        vg += fc1W[(64 + j) * 64 + k] * fc2W[k];
    }
    vdnn[j] = vd;
    float part = ge * vg + fc1b[j] * fc2W[j];
    for (int o = 32; o > 0; o >>= 1) part += __shfl_down(part, o);
    if (j == 0) cons[0] = part + fc2b[0];
}

// ---------------- output: out[i] = sum_j relu(h*sc+sh)*vdnn + C ----------------
__global__ __launch_bounds__(256) void out_kernel(const float* __restrict__ H,
    const float* __restrict__ scale, const float* __restrict__ shift,
    const float* __restrict__ vdnn, const float* __restrict__ cons,
    float* __restrict__ out)
{
    const int lane = threadIdx.x & 63;
    const int grp = threadIdx.x >> 6;
    const int i = blockIdx.x * 4 + grp;
    float x = H[(size_t)i * 64 + lane] * scale[lane] + shift[lane];
    x = fmaxf(x, 0.f) * vdnn[lane];
    for (int o = 32; o > 0; o >>= 1) x += __shfl_down(x, o);
    if (lane == 0) out[i] = x + cons[0];
}

extern "C" void kernel_launch(void* const* d_in, const int* in_sizes, int n_in,
                              void* d_out, int out_size, void* d_ws, size_t ws_size,
                              hipStream_t stream)
{
    const float* x1    = (const float*)d_in[0];
    const float* x2    = (const float*)d_in[1];
    const int*   ei    = (const int*)d_in[2];
    const float* dnnW  = (const float*)d_in[3];
    // d_in[4] = dnn_b: cancels inside BatchNorm, unused
    const float* gamma = (const float*)d_in[5];
    const float* beta  = (const float*)d_in[6];
    const float* g1W   = (const float*)d_in[7];
    const float* g1b   = (const float*)d_in[8];
    const float* g2W   = (const float*)d_in[9];
    const float* g2b   = (const float*)d_in[10];
    const float* fc1W  = (const float*)d_in[11];
    const float* fc1b  = (const float*)d_in[12];
    const float* fc2W  = (const float*)d_in[13];
    const float* fc2b  = (const float*)d_in[14];

    float* ws      = (float*)d_ws;
    float* h1      = ws;                    // 3,200,000 f
    float* hdnn    = h1 + 3200000;          // 1,048,576 f
    float* dis     = hdnn + 1048576;        // 50,048 f
    int*   offs    = (int*)(dis + 50048);   // 50,048 i
    int*   cursor  = offs + 50048;          // 50,048 i
    int*   erow    = cursor + 50048;        // 800,000 i
    int*   bsum    = erow + 800000;         // 256 i
    int*   boff    = bsum + 256;            // 256 i
    int*   cnt     = boff + 256;            // 50,048 i  <- zero region start
    float* wraw    = (float*)(cnt + 50048); // 50,048 f
    float* bnsum   = wraw + 50048;          // 64
    float* bnsumsq = bnsum + 64;            // 64
    float* svec    = bnsumsq + 64;          // 64        <- zero region end
    float* scale   = svec + 64;
    float* shift   = scale + 64;
    float* vdnn    = shift + 64;
    float* cons    = vdnn + 64;

    const size_t zero_bytes = (size_t)(50048 + 50048 + 192) * sizeof(int);
    hipMemsetAsync(cnt, 0, zero_bytes, stream);

    dnn_gemm<<<256, 256, 0, stream>>>(x1, dnnW, hdnn);
    bn_stats<<<256, 256, 0, stream>>>(hdnn, bnsum, bnsumsq);
    gcn1_gemm<<<196, 256, 0, stream>>>(x2, g1W, h1);
    cnt_kernel<<<1024, 256, 0, stream>>>(ei, cnt);
    dis_kernel<<<196, 256, 0, stream>>>(cnt, dis);
    scan1<<<196, 256, 0, stream>>>(cnt, bsum);
    scan2<<<1, 256, 0, stream>>>(bsum, boff);
    scan3<<<196, 256, 0, stream>>>(cnt, boff, offs, cursor);
    scatter_kernel<<<1024, 256, 0, stream>>>(ei, dis, cursor, erow, wraw);
    gather_node<<<2048, 256, 0, stream>>>(offs, cnt, erow, dis, wraw, h1, g1b, svec);
    finalize_kernel<<<1, 64, 0, stream>>>(bnsum, bnsumsq, gamma, beta, svec,
                                          g2W, g2b, fc1W, fc1b, fc2W, fc2b,
                                          scale, shift, vdnn, cons);
    out_kernel<<<4096, 256, 0, stream>>>(hdnn, scale, shift, vdnn, cons,
                                         (float*)d_out);
}